// Round 8
// baseline (39.958 us; speedup 1.0000x reference)
//
#include <hip/hip_runtime.h>
#include <hip/hip_bf16.h>

#define N_TOKENS   262144
#define DIM        64
#define KCODES     512
#define OUT_ELEMS  (N_TOKENS * DIM)          // 16777216
#define LOSS_SCALE (1.25f / 16777216.0f)

typedef float  f32x4 __attribute__((ext_vector_type(4)));
typedef float  f32x8 __attribute__((ext_vector_type(8)));
typedef short  s16x8 __attribute__((ext_vector_type(8)));
typedef unsigned short u16x8 __attribute__((ext_vector_type(8)));

static __device__ __forceinline__ unsigned short f2bf(float f) {
    unsigned int u = __builtin_bit_cast(unsigned int, f);
    u += 0x7fffu + ((u >> 16) & 1u);          // round-to-nearest-even
    return (unsigned short)(u >> 16);
}

// Prep: codebook -> bf16(-2c) in MFMA-fragment order (ws), ||c||^2+2 (ws), zero loss.
// Fragment element index for (code k, dim d):
//   t=k>>4, li=k&15, kk=d>>5, hi=(d>>3)&3, j=d&7 -> ((t*2+kk)*64 + hi*16+li)*8 + j
// +2 bias keeps every distance key strictly positive so uint cmp == float cmp.
__global__ void vq_prep(const float* __restrict__ cb,
                        unsigned short* __restrict__ cbf,
                        float* __restrict__ c2,
                        float* __restrict__ out_loss) {
    const int k = blockIdx.x;       // 512 blocks, one code each
    const int d = threadIdx.x;      // 64 threads (one wave)
    const float v = cb[k * DIM + d];
    float s = v * v;
    #pragma unroll
    for (int sh = 1; sh < 64; sh <<= 1) s += __shfl_xor(s, sh, 64);
    if (d == 0) c2[k] = s + 2.0f;

    const int t = k >> 4, li = k & 15;
    const int kk = d >> 5, hi = (d >> 3) & 3, j = d & 7;
    const int slot = (t * 2 + kk) * 64 + hi * 16 + li;
    cbf[slot * 8 + j] = f2bf(-2.0f * v);

    if (k == 0 && d == 0) *out_loss = 0.0f;
}

// Main: 512 blocks x 1024 threads (16 waves), 32 tokens/wave = 512 tokens/block.
// LDS 70 KiB -> 2 blocks/CU resident; VGPR <= 64 -> 8 waves/SIMD; together
// 32 waves/CU (HW max). The two resident blocks desynchronize: one block's
// 64 KiB staging overlaps the other's compute/IO. One barrier per block.
// NOTE: min-waves>=8 in launch_bounds spilled in R3/R6 -> keep (1024, 4).
__global__ __launch_bounds__(1024, 4) void vq_main(
    const float* __restrict__ z,
    const float* __restrict__ cb,              // fp32 codebook (exact gather)
    const unsigned short* __restrict__ cbf,    // bf16(-2c), fragment order
    const float* __restrict__ c2g,             // ||c||^2 + 2
    float* __restrict__ out)
{
    __shared__ unsigned short cbs[KCODES * DIM];   // 64 KiB, fragment order
    __shared__ float c2s[KCODES];                  // 2 KiB
    __shared__ int   keysl[16][32];                // 2 KiB
    __shared__ float lpart[16];

    const int tid  = threadIdx.x;
    const int wave = tid >> 6;
    const int lane = tid & 63;
    const int li   = lane & 15;   // A-row / C-col lane index
    const int hi   = lane >> 4;   // k-group

    // ---- stage fragment-ordered codebook: pure linear copy, conflict-free ----
    #pragma unroll
    for (int i = 0; i < 4; ++i)
        ((u16x8*)cbs)[i * 1024 + tid] = ((const u16x8*)cbf)[i * 1024 + tid];
    if (tid < KCODES) c2s[tid] = c2g[tid];
    __syncthreads();   // the ONLY block-wide barrier before the loss epilogue

    const int token0 = blockIdx.x * 512 + wave * 32;
    float lossp = 0.f;

    // ---- load z, build bf16 A-fragments, ||z||^2 per row ----
    s16x8 af[2][2];
    float z2[2];
    #pragma unroll
    for (int m = 0; m < 2; ++m) {
        float zs = 0.f;
        #pragma unroll
        for (int kk = 0; kk < 2; ++kk) {
            const float* p = z + (size_t)(token0 + m * 16 + li) * DIM + kk * 32 + hi * 8;
            const f32x8 v = *(const f32x8*)p;
            s16x8 a;
            #pragma unroll
            for (int j = 0; j < 8; ++j) {
                zs += v[j] * v[j];
                a[j] = (short)f2bf(v[j]);
            }
            af[m][kk] = a;
        }
        zs += __shfl_xor(zs, 16, 64);
        zs += __shfl_xor(zs, 32, 64);
        z2[m] = zs;
    }

    // ---- argmin over 512 codes; B-fragments from LDS ----
    unsigned bkey[2][4];
    #pragma unroll
    for (int m = 0; m < 2; ++m)
        #pragma unroll
        for (int r = 0; r < 4; ++r) bkey[m][r] = 0xFFFFFFFFu;

    #pragma unroll 4
    for (int t = 0; t < 32; ++t) {
        const s16x8 b0 = *(const s16x8*)&cbs[((t * 2 + 0) * 64 + lane) * 8];
        const s16x8 b1 = *(const s16x8*)&cbs[((t * 2 + 1) * 64 + lane) * 8];
        const float cv = c2s[t * 16 + li];
        const unsigned code = (unsigned)(t * 16 + li);
        #pragma unroll
        for (int m = 0; m < 2; ++m) {
            f32x4 acc = {cv, cv, cv, cv};
            acc = __builtin_amdgcn_mfma_f32_16x16x32_bf16(af[m][0], b0, acc, 0, 0, 0);
            acc = __builtin_amdgcn_mfma_f32_16x16x32_bf16(af[m][1], b1, acc, 0, 0, 0);
            // acc[r] = ||c||^2 + 2 - 2 z.c for row (m*16 + hi*4 + r), col code
            #pragma unroll
            for (int r = 0; r < 4; ++r) {
                const unsigned key = (__builtin_bit_cast(unsigned, acc[r]) & ~511u) | code;
                if (key < bkey[m][r]) bkey[m][r] = key;   // v_and_or + v_min_u32
            }
        }
    }

    // ---- reduce across the 16 li-lanes (positive-float keys: uint min) ----
    #pragma unroll
    for (int sh = 1; sh < 16; sh <<= 1) {
        #pragma unroll
        for (int m = 0; m < 2; ++m)
            #pragma unroll
            for (int r = 0; r < 4; ++r) {
                const unsigned ok = (unsigned)__shfl_xor((int)bkey[m][r], sh, 64);
                if (ok < bkey[m][r]) bkey[m][r] = ok;
            }
    }

    // rows m*16 + hi*4 + r -> key; wave-private slab, no barrier needed
    if (li == 0) {
        #pragma unroll
        for (int m = 0; m < 2; ++m)
            #pragma unroll
            for (int r = 0; r < 4; ++r)
                keysl[wave][m * 16 + hi * 4 + r] = (int)bkey[m][r];
    }

    // ---- gather exact fp32 rows (L2-hit), write z_q, loss from key ----
    #pragma unroll
    for (int m = 0; m < 2; ++m) {
        const unsigned key = (unsigned)keysl[wave][m * 16 + li];  // row = m*16+li
        const int code = (int)(key & 511u);
        if (hi == 0)
            lossp += (__builtin_bit_cast(float, key & ~511u) - 2.0f) + z2[m];
        const float* cbr = cb + code * DIM + hi * 8;
        const f32x8 q0 = *(const f32x8*)(cbr);
        const f32x8 q1 = *(const f32x8*)(cbr + 32);
        float* op = out + (size_t)(token0 + m * 16 + li) * DIM + hi * 8;
        *(f32x8*)(op)      = q0;
        *(f32x8*)(op + 32) = q1;
    }

    // ---- loss reduction: wave shuffle -> per-wave slot -> single atomic ----
    #pragma unroll
    for (int sh = 1; sh < 64; sh <<= 1) lossp += __shfl_xor(lossp, sh, 64);
    if (lane == 0) lpart[wave] = lossp;
    __syncthreads();
    if (tid == 0) {
        float s = 0.f;
        #pragma unroll
        for (int w = 0; w < 16; ++w) s += lpart[w];
        atomicAdd(out + OUT_ELEMS, s * LOSS_SCALE);
    }
}

extern "C" void kernel_launch(void* const* d_in, const int* in_sizes, int n_in,
                              void* d_out, int out_size, void* d_ws, size_t ws_size,
                              hipStream_t stream) {
    const float* z  = (const float*)d_in[0];
    const float* cb = (const float*)d_in[1];
    float* out = (float*)d_out;

    unsigned short* cbf = (unsigned short*)d_ws;                               // 64 KiB
    float* c2 = (float*)((char*)d_ws + KCODES * DIM * sizeof(unsigned short)); // 2 KiB

    vq_prep<<<KCODES, 64, 0, stream>>>(cb, cbf, c2, out + OUT_ELEMS);
    vq_main<<<N_TOKENS / 512, 1024, 0, stream>>>(z, cb, cbf, c2, out);
}

// Round 9
// 37.798 us; speedup vs baseline: 1.0571x; 1.0571x over previous
//
#include <hip/hip_runtime.h>
#include <hip/hip_bf16.h>

#define N_TOKENS   262144
#define DIM        64
#define KCODES     512
#define OUT_ELEMS  (N_TOKENS * DIM)          // 16777216
#define LOSS_SCALE (1.25f / 16777216.0f)

typedef float  f32x4 __attribute__((ext_vector_type(4)));
typedef float  f32x8 __attribute__((ext_vector_type(8)));
typedef int    i32x4 __attribute__((ext_vector_type(4)));
typedef int    i32x2 __attribute__((ext_vector_type(2)));

// Pack 8 f32 -> 8 fp8 e4m3 bytes (j-th byte = fp8(v[j])) via v_cvt_pk_fp8_f32.
static __device__ __forceinline__ long pack_fp8x8(const f32x8 v) {
    int lo = __builtin_amdgcn_cvt_pk_fp8_f32(v[0], v[1], 0, false);
    lo     = __builtin_amdgcn_cvt_pk_fp8_f32(v[2], v[3], lo, true);
    int hi = __builtin_amdgcn_cvt_pk_fp8_f32(v[4], v[5], 0, false);
    hi     = __builtin_amdgcn_cvt_pk_fp8_f32(v[6], v[7], hi, true);
    i32x2 r = {lo, hi};
    return __builtin_bit_cast(long, r);
}

// Prep: codebook -> fp8(-256*c) in MFMA-fragment order (ws); c2 = 128*||c||^2+256;
// zero loss slot. Fragment byte index for (code k, dim d):
//   t=k>>4, li=k&15, kk=d>>5, hi=(d>>3)&3, j=d&7 -> ((t*2+kk)*64 + hi*16+li)*8 + j
// Scale 2^7 lifts |2c|<=1/256 out of the e4m3 subnormal floor (values +-0.5,
// normal with 3-bit mantissa). Uniform positive scale preserves the argmin.
__global__ void vq_prep(const float* __restrict__ cb,
                        unsigned char* __restrict__ cbf,
                        float* __restrict__ c2,
                        float* __restrict__ out_loss) {
    const int k = blockIdx.x;       // 512 blocks, one code each
    const int d = threadIdx.x;      // 64 threads (one wave)
    const float v = cb[k * DIM + d];
    float s = v * v;
    #pragma unroll
    for (int sh = 1; sh < 64; sh <<= 1) s += __shfl_xor(s, sh, 64);
    if (d == 0) c2[k] = 128.0f * s + 256.0f;   // keys stay strictly positive

    const int t = k >> 4, li = k & 15;
    const int kk = d >> 5, hi = (d >> 3) & 3, j = d & 7;
    const int slot = (t * 2 + kk) * 64 + hi * 16 + li;
    const int p = __builtin_amdgcn_cvt_pk_fp8_f32(-256.0f * v, 0.0f, 0, false);
    cbf[slot * 8 + j] = (unsigned char)(p & 0xFF);

    if (k == 0 && d == 0) *out_loss = 0.0f;
}

// Main: 1024 blocks x 512 threads (8 waves), 32 tokens/wave = 256 tokens/block.
// fp8 codebook in LDS = 32 KiB; total LDS ~35 KiB -> 3-4 blocks/CU = 24-32
// waves/CU (vs 16 for the 70 KiB bf16 variant). z-loads issue BEFORE the
// staging copy so HBM latency hides under L2->LDS staging. One barrier.
__global__ __launch_bounds__(512, 4) void vq_main(
    const float* __restrict__ z,
    const float* __restrict__ cb,              // fp32 codebook (exact gather)
    const unsigned char* __restrict__ cbf,     // fp8(-256c), fragment order
    const float* __restrict__ c2g,             // 128*||c||^2 + 256
    float* __restrict__ out)
{
    __shared__ unsigned char cbs[KCODES * DIM];   // 32 KiB, fragment order
    __shared__ float c2s[KCODES];                 // 2 KiB
    __shared__ int   keysl[8][32];                // 1 KiB
    __shared__ float lpart[8];

    const int tid  = threadIdx.x;
    const int wave = tid >> 6;
    const int lane = tid & 63;
    const int li   = lane & 15;   // A-row / C-col lane index
    const int hi   = lane >> 4;   // k-group

    const int token0 = blockIdx.x * 256 + wave * 32;

    // ---- issue z loads FIRST (overlap HBM latency with staging below) ----
    const float* zb = z + (size_t)token0 * DIM + li * DIM + hi * 8;
    const f32x8 v00 = *(const f32x8*)(zb);               // m=0, k 0..31 slice
    const f32x8 v01 = *(const f32x8*)(zb + 32);          // m=0, k 32..63
    const f32x8 v10 = *(const f32x8*)(zb + 16 * DIM);    // m=1
    const f32x8 v11 = *(const f32x8*)(zb + 16 * DIM + 32);

    // ---- stage fp8 codebook (linear, conflict-free) + c2 ----
    #pragma unroll
    for (int i = 0; i < 4; ++i)
        ((i32x4*)cbs)[i * 512 + tid] = ((const i32x4*)cbf)[i * 512 + tid];
    c2s[tid] = c2g[tid];   // tid < 512 == KCODES

    // ---- convert z -> fp8 A-fragments + exact fp32 ||z||^2 ----
    long af[2][2];
    float z2[2];
    {
        float zs = 0.f;
        #pragma unroll
        for (int j = 0; j < 8; ++j) zs += v00[j] * v00[j] + v01[j] * v01[j];
        af[0][0] = pack_fp8x8(v00);
        af[0][1] = pack_fp8x8(v01);
        zs += __shfl_xor(zs, 16, 64);
        zs += __shfl_xor(zs, 32, 64);
        z2[0] = zs;
    }
    {
        float zs = 0.f;
        #pragma unroll
        for (int j = 0; j < 8; ++j) zs += v10[j] * v10[j] + v11[j] * v11[j];
        af[1][0] = pack_fp8x8(v10);
        af[1][1] = pack_fp8x8(v11);
        zs += __shfl_xor(zs, 16, 64);
        zs += __shfl_xor(zs, 32, 64);
        z2[1] = zs;
    }
    __syncthreads();   // staging complete

    // ---- argmin over 512 codes; fp8 B-fragments from LDS (b64 reads) ----
    unsigned bkey[2][4];
    #pragma unroll
    for (int m = 0; m < 2; ++m)
        #pragma unroll
        for (int r = 0; r < 4; ++r) bkey[m][r] = 0xFFFFFFFFu;

    #pragma unroll 4
    for (int t = 0; t < 32; ++t) {
        const long b0 = *(const long*)&cbs[((t * 2 + 0) * 64 + lane) * 8];
        const long b1 = *(const long*)&cbs[((t * 2 + 1) * 64 + lane) * 8];
        const float cv = c2s[t * 16 + li];
        const unsigned code = (unsigned)(t * 16 + li);
        #pragma unroll
        for (int m = 0; m < 2; ++m) {
            f32x4 acc = {cv, cv, cv, cv};
            acc = __builtin_amdgcn_mfma_f32_16x16x32_fp8_fp8(af[m][0], b0, acc, 0, 0, 0);
            acc = __builtin_amdgcn_mfma_f32_16x16x32_fp8_fp8(af[m][1], b1, acc, 0, 0, 0);
            // acc[r] = 128*(||c||^2 - 2 z.c) + 256 for row (m*16+hi*4+r), col code
            #pragma unroll
            for (int r = 0; r < 4; ++r) {
                const unsigned key = (__builtin_bit_cast(unsigned, acc[r]) & ~511u) | code;
                if (key < bkey[m][r]) bkey[m][r] = key;   // v_and_or + v_min_u32
            }
        }
    }

    // ---- reduce across the 16 li-lanes (positive-float keys: uint min) ----
    #pragma unroll
    for (int sh = 1; sh < 16; sh <<= 1) {
        #pragma unroll
        for (int m = 0; m < 2; ++m)
            #pragma unroll
            for (int r = 0; r < 4; ++r) {
                const unsigned ok = (unsigned)__shfl_xor((int)bkey[m][r], sh, 64);
                if (ok < bkey[m][r]) bkey[m][r] = ok;
            }
    }

    // rows m*16 + hi*4 + r -> key; wave-private slab, same-wave LDS is ordered
    if (li == 0) {
        #pragma unroll
        for (int m = 0; m < 2; ++m)
            #pragma unroll
            for (int r = 0; r < 4; ++r)
                keysl[wave][m * 16 + hi * 4 + r] = (int)bkey[m][r];
    }

    // ---- gather exact fp32 rows (L2-hit), write z_q, loss from key ----
    float lossp = 0.f;
    #pragma unroll
    for (int m = 0; m < 2; ++m) {
        const unsigned key = (unsigned)keysl[wave][m * 16 + li];  // row = m*16+li
        const int code = (int)(key & 511u);
        if (hi == 0) {
            const float kf = __builtin_bit_cast(float, key & ~511u);
            // dist~ = ||c||^2 - 2 z.c = (kf - 256)/128 ; token loss = dist~ + ||z||^2
            lossp += __builtin_fmaf(kf - 256.0f, 0.0078125f, z2[m]);
        }
        const float* cbr = cb + code * DIM + hi * 8;
        const f32x8 q0 = *(const f32x8*)(cbr);
        const f32x8 q1 = *(const f32x8*)(cbr + 32);
        float* op = out + (size_t)(token0 + m * 16 + li) * DIM + hi * 8;
        *(f32x8*)(op)      = q0;
        *(f32x8*)(op + 32) = q1;
    }

    // ---- loss reduction: wave shuffle -> per-wave slot -> single atomic ----
    #pragma unroll
    for (int sh = 1; sh < 64; sh <<= 1) lossp += __shfl_xor(lossp, sh, 64);
    if (lane == 0) lpart[wave] = lossp;
    __syncthreads();
    if (tid == 0) {
        float s = 0.f;
        #pragma unroll
        for (int w = 0; w < 8; ++w) s += lpart[w];
        atomicAdd(out + OUT_ELEMS, s * LOSS_SCALE);
    }
}

extern "C" void kernel_launch(void* const* d_in, const int* in_sizes, int n_in,
                              void* d_out, int out_size, void* d_ws, size_t ws_size,
                              hipStream_t stream) {
    const float* z  = (const float*)d_in[0];
    const float* cb = (const float*)d_in[1];
    float* out = (float*)d_out;

    unsigned char* cbf = (unsigned char*)d_ws;                       // 32 KiB
    float* c2 = (float*)((char*)d_ws + KCODES * DIM);                // 2 KiB

    vq_prep<<<KCODES, 64, 0, stream>>>(cb, cbf, c2, out + OUT_ELEMS);
    vq_main<<<N_TOKENS / 256, 512, 0, stream>>>(z, cb, cbf, c2, out);
}